// Round 15
// baseline (28.596 us; speedup 1.0000x reference)
//
#include <hip/hip_runtime.h>

// CTC batch cost, B=256 T=512 C=256 L=64 (S=129).
// R15: NO staging. 2 waves/block (wid0=fwd DP t=0..255, wid1=bwd DP
// t=511..256). Each wave gathers its own per-lane label prob directly to
// registers (global_load_dword, 1 dword/lane/row) with a 3-bank named-reg
// pipeline (a/b/c x 8, 3 groups deep; WAR on regs = the pipeline; compiler
// emits precise per-reg vmcnt waits -- ordinary tracked loads, unlike R8's
// untrackable LDS-DMA). Blank channel: 4 prologue vector loads + compile-
// time readlane (R3 pattern). Rationale: FETCH ~70MB << 128MB across all
// rounds (L3-resident input; HBM not the wall) while every staging variant
// returned 1 KB/row into the CU and pinned at ~20 GB/s/CU; the DP needs
// only 260 B/row. R6's version of this spilled (arrays); named regs fix it.
// DP math: f64 linear domain, DPP shifts, log2 cut combine (absmax 0.0
// R6-R14).

constexpr int Bc = 256;
constexpr int Tc = 512;
constexpr int Cc = 256;
constexpr int Lc = 64;

#define EPSF (1e-7f)
#define NEGF (-1e30f)

__device__ __forceinline__ float flog2(float x) {
    float r; asm("v_log_f32 %0, %1" : "=v"(r) : "v"(x)); return r;
}
__device__ __forceinline__ float fexp2(float x) {
    float r; asm("v_exp_f32 %0, %1" : "=v"(r) : "v"(x)); return r;
}
__device__ __forceinline__ float lse2(float a, float b) {
    float m = fmaxf(a, b);
    float d = fminf(a, b) - m;
    return m + flog2(1.f + fexp2(d));
}
__device__ __forceinline__ float dlog2(double x) {
    if (!(x > 1e-300)) return NEGF;
    const int hb = __double2hiint(x);
    const int lb = __double2loint(x);
    const int e  = ((hb >> 20) & 0x7FF) - 1022;
    const double m = __hiloint2double((hb & 0x800FFFFF) | (1022 << 20), lb);
    return flog2((float)m) + (float)e;            // m in [0.5, 1)
}
__device__ __forceinline__ double dpp_up1_d(double old, double src) {   // lane i <- i-1
    const int rl = __builtin_amdgcn_update_dpp(
        __double2loint(old), __double2loint(src), 0x138, 0xF, 0xF, false);
    const int rh = __builtin_amdgcn_update_dpp(
        __double2hiint(old), __double2hiint(src), 0x138, 0xF, 0xF, false);
    return __hiloint2double(rh, rl);
}
__device__ __forceinline__ double dpp_dn1_d(double old, double src) {   // lane i <- i+1
    const int rl = __builtin_amdgcn_update_dpp(
        __double2loint(old), __double2loint(src), 0x130, 0xF, 0xF, false);
    const int rh = __builtin_amdgcn_update_dpp(
        __double2hiint(old), __double2hiint(src), 0x130, 0xF, 0xF, false);
    return __hiloint2double(rh, rl);
}
__device__ __forceinline__ float rdlane(float v, int idx) {
    return __int_as_float(__builtin_amdgcn_readlane(__float_as_int(v), idx));
}

__global__ __launch_bounds__(128, 1) void ctc_fb_kernel(
        const int* __restrict__ y_true,
        const float* __restrict__ y_pred,
        float* __restrict__ out)
{
    const int b    = blockIdx.x;
    const int lane = threadIdx.x & 63;
    const int wid  = threadIdx.x >> 6;

    __shared__ float Cl[64], Ch[64];
    __shared__ float CexS;

    const float* __restrict__ bbase = y_pred + (size_t)b * Tc * Cc;
    const int lab  = y_true[b * Lc + lane];
    const int labp = __shfl_up(lab, 1);
    const int labn = __shfl_down(lab, 1);

    // Blank-channel vectors: local step u -> t (fwd: u, bwd: 511-u);
    // bv[k][j] corresponds to u = 64k + j.
    const float bv0 = bbase[(size_t)(wid ? (511 -       lane) : (      lane)) * Cc + (Cc - 1)] + EPSF;
    const float bv1 = bbase[(size_t)(wid ? (447 -       lane) : ( 64 + lane)) * Cc + (Cc - 1)] + EPSF;
    const float bv2 = bbase[(size_t)(wid ? (383 -       lane) : (128 + lane)) * Cc + (Cc - 1)] + EPSF;
    const float bv3 = bbase[(size_t)(wid ? (319 -       lane) : (192 + lane)) * Cc + (Cc - 1)] + EPSF;

    // Per-lane label-column pointer; local step u at GL(g,j), u = 8g+j.
    const float* __restrict__ gL0 =
        wid ? (bbase + (size_t)(Tc - 1) * Cc + lab) : (bbase + lab);
    const ptrdiff_t stpL = wid ? -(ptrdiff_t)Cc : (ptrdiff_t)Cc;

#define GL(g, j) gL0[stpL * (8 * (g) + (j))]
#define LOADB(p, g)                                                  \
    p##0 = GL(g,0); p##1 = GL(g,1); p##2 = GL(g,2); p##3 = GL(g,3);  \
    p##4 = GL(g,4); p##5 = GL(g,5); p##6 = GL(g,6); p##7 = GL(g,7);
#define BVG(g) ((g) >= 24 ? bv3 : (g) >= 16 ? bv2 : (g) >= 8 ? bv1 : bv0)

    float a0, a1, a2, a3, a4, a5, a6, a7;
    float b0, b1, b2, b3, b4, b5, b6, b7;
    float c0, c1, c2, c3, c4, c5, c6, c7;

    double lo = 0.0, hi = 0.0, ex = 0.0;

    LOADB(a, 0) LOADB(b, 1) LOADB(c, 2)

    if (wid == 0) {
        // ---------------- forward: rows 0..255 ----------------
        const bool allowF = (lane >= 1) && (lab != labp);
        auto stepF = [&](float pB, float pLf) {
            const double pBd = (double)pB, pL = (double)(pLf + EPSF);
            const double prevHi = dpp_up1_d(0.0, hi);
            const double sk  = allowF ? prevHi : 0.0;
            const double nlo = (lo + prevHi) * pBd;
            const double nhi = (hi + lo + sk) * pL;
            ex = (ex + hi) * pBd;    // real only at lane 63 (127->128)
            hi = nhi; lo = nlo;
        };
#define SF(g, j, v) stepF(rdlane(BVG(g), (8 * (g) + (j)) & 63), v);
#define ITERF(g, p)                                                  \
        SF(g, 0, p##0) SF(g, 1, p##1) SF(g, 2, p##2) SF(g, 3, p##3)  \
        SF(g, 4, p##4) SF(g, 5, p##5) SF(g, 6, p##6) SF(g, 7, p##7)
        // group 0: row 0 is the DP init
        lo = (lane == 0) ? (double)rdlane(bv0, 0) : 0.0;       // alpha0(0)
        hi = (lane == 0) ? (double)(a0 + EPSF) : 0.0;          // alpha0(1)
        SF(0, 1, a1) SF(0, 2, a2) SF(0, 3, a3) SF(0, 4, a4)
        SF(0, 5, a5) SF(0, 6, a6) SF(0, 7, a7)
        LOADB(a, 3)
        ITERF( 1, b) LOADB(b,  4)
        ITERF( 2, c) LOADB(c,  5)
        ITERF( 3, a) LOADB(a,  6)
        ITERF( 4, b) LOADB(b,  7)
        ITERF( 5, c) LOADB(c,  8)
        ITERF( 6, a) LOADB(a,  9)
        ITERF( 7, b) LOADB(b, 10)
        ITERF( 8, c) LOADB(c, 11)
        ITERF( 9, a) LOADB(a, 12)
        ITERF(10, b) LOADB(b, 13)
        ITERF(11, c) LOADB(c, 14)
        ITERF(12, a) LOADB(a, 15)
        ITERF(13, b) LOADB(b, 16)
        ITERF(14, c) LOADB(c, 17)
        ITERF(15, a) LOADB(a, 18)
        ITERF(16, b) LOADB(b, 19)
        ITERF(17, c) LOADB(c, 20)
        ITERF(18, a) LOADB(a, 21)
        ITERF(19, b) LOADB(b, 22)
        ITERF(20, c) LOADB(c, 23)
        ITERF(21, a) LOADB(a, 24)
        ITERF(22, b) LOADB(b, 25)
        ITERF(23, c) LOADB(c, 26)
        ITERF(24, a) LOADB(a, 27)
        ITERF(25, b) LOADB(b, 28)
        ITERF(26, c) LOADB(c, 29)
        ITERF(27, a) LOADB(a, 30)
        ITERF(28, b) LOADB(b, 31)
        ITERF(29, c)
        ITERF(30, a)
        ITERF(31, b)
#undef SF
#undef ITERF
    } else {
        // ---------------- backward: local rows 0..255 (t = 511..256) ------
        const bool allowB = (lane < 63) && (labn != lab);
        auto stepB = [&](float pB, float pLf) {
            const double pBd = (double)pB, pL = (double)(pLf + EPSF);
            const double nlo_s = dpp_dn1_d(ex, lo);   // B(2l+2); l63 <- ex
            const double nhi_s = dpp_dn1_d(0.0, hi);  // B(2l+3); l63 <- 0
            const double sk = allowB ? nhi_s : 0.0;
            const double l2 = (lo + hi) * pBd;
            const double h2 = (hi + nlo_s + sk) * pL;
            ex = ex * pBd;
            lo = l2; hi = h2;
        };
#define SB(g, j, v) stepB(rdlane(BVG(g), (8 * (g) + (j)) & 63), v);
#define ITERB(g, p)                                                  \
        SB(g, 0, p##0) SB(g, 1, p##1) SB(g, 2, p##2) SB(g, 3, p##3)  \
        SB(g, 4, p##4) SB(g, 5, p##5) SB(g, 6, p##6) SB(g, 7, p##7)
        // group 0: local row 0 (t=511) is the DP init
        ex = (double)rdlane(bv0, 0);                            // beta511(128)
        hi = (lane == 63) ? (double)(a0 + EPSF) : 0.0;          // beta511(127)
        lo = 0.0;
        SB(0, 1, a1) SB(0, 2, a2) SB(0, 3, a3) SB(0, 4, a4)
        SB(0, 5, a5) SB(0, 6, a6) SB(0, 7, a7)
        LOADB(a, 3)
        ITERB( 1, b) LOADB(b,  4)
        ITERB( 2, c) LOADB(c,  5)
        ITERB( 3, a) LOADB(a,  6)
        ITERB( 4, b) LOADB(b,  7)
        ITERB( 5, c) LOADB(c,  8)
        ITERB( 6, a) LOADB(a,  9)
        ITERB( 7, b) LOADB(b, 10)
        ITERB( 8, c) LOADB(c, 11)
        ITERB( 9, a) LOADB(a, 12)
        ITERB(10, b) LOADB(b, 13)
        ITERB(11, c) LOADB(c, 14)
        ITERB(12, a) LOADB(a, 15)
        ITERB(13, b) LOADB(b, 16)
        ITERB(14, c) LOADB(c, 17)
        ITERB(15, a) LOADB(a, 18)
        ITERB(16, b) LOADB(b, 19)
        ITERB(17, c) LOADB(c, 20)
        ITERB(18, a) LOADB(a, 21)
        ITERB(19, b) LOADB(b, 22)
        ITERB(20, c) LOADB(c, 23)
        ITERB(21, a) LOADB(a, 24)
        ITERB(22, b) LOADB(b, 25)
        ITERB(23, c) LOADB(c, 26)
        ITERB(24, a) LOADB(a, 27)
        ITERB(25, b) LOADB(b, 28)
        ITERB(26, c) LOADB(c, 29)
        ITERB(27, a) LOADB(a, 30)
        ITERB(28, b) LOADB(b, 31)
        ITERB(29, c)
        ITERB(30, a)
        ITERB(31, b)
#undef SB
#undef ITERB
        // cut combine half-step: C(s) = B(s) + B(s+1) + allowB(s)*B(s+2),
        // stored log2-domain (R4 lesson: anti-aligned maxima).
        const double nlo_s = dpp_dn1_d(ex, lo);
        const double nhi_s = dpp_dn1_d(0.0, hi);
        const double sk = allowB ? nhi_s : 0.0;
        Cl[lane] = dlog2(lo + hi);
        Ch[lane] = dlog2(hi + nlo_s + sk);
        if (lane == 63) CexS = dlog2(ex);
    }
#undef GL
#undef LOADB
#undef BVG

    __syncthreads();

    if (wid == 0) {
        const float w1 = dlog2(lo) + Cl[lane];
        const float w2 = dlog2(hi) + Ch[lane];
        float w = lse2(w1, w2);
        if (lane == 63) w = lse2(w, dlog2(ex) + CexS);
        #pragma unroll
        for (int off = 32; off; off >>= 1) w = lse2(w, __shfl_xor(w, off));
        if (lane == 0)
            out[b] = -0.69314718055994530942f * w;     // ln2 * log2 -> ln
    }
}

extern "C" void kernel_launch(void* const* d_in, const int* in_sizes, int n_in,
                              void* d_out, int out_size, void* d_ws, size_t ws_size,
                              hipStream_t stream) {
    const int*   y_true = (const int*)d_in[0];
    const float* y_pred = (const float*)d_in[1];
    float*       out    = (float*)d_out;
    ctc_fb_kernel<<<dim3(Bc), dim3(128), 0, stream>>>(y_true, y_pred, out);
}